// Round 4
// baseline (9325.658 us; speedup 1.0000x reference)
//
#include <hip/hip_runtime.h>
#include <stdint.h>

typedef __attribute__((ext_vector_type(8))) short bf16x8;
typedef __attribute__((ext_vector_type(4))) float f32x4;
typedef unsigned short u16;

#define MFMA16(a,b,c) __builtin_amdgcn_mfma_f32_16x16x32_bf16((a),(b),(c),0,0,0)

static constexpr int T_STEPS = 256;
static constexpr int BATCH   = 2048;
static constexpr int YDIM    = 20;
static constexpr int BS      = 16;             // batch rows per WG
static constexpr int NWG     = BATCH / BS;     // 128 WGs x 1024 threads

// ws layout: per-wave fragment blocks. 92 frags/wave, each frag = 1KB
// (64 lanes x 16B). Frag f of wave w at ws[(w*92+f)*512 ...].
// B-frag: lane L holds W[row = ct*16 + (L&15)][k = kt*32 + (L>>4)*8 + j].
// f 0..26 : GRU0  g=f/9 (r,z,n), kk=f%9; kk<8: Whh0 ktile kk; kk==8: Wih0 (K pad 20->32)
// f 27..74: GRU1  ff=f-27, g=ff>>4, kk=ff&15; kk<8: Whh1 kt=kk; else Wih1 kt=kk-8
// f 75..82: W1 ct=w, kt=f-75
// f 83..90: W2 ct=w, kt=f-83
// f 91    : W3 ct=w&1, kt=w>>1 (rows pad 20->32)
static constexpr int FRAGS    = 92;
static constexpr int WAVE_U16 = FRAGS * 512;        // 47104
static constexpr int WS_TOTAL = 16 * WAVE_U16;      // 753664 u16 = 1.44 MB

__device__ __forceinline__ u16 f2bf(float x) {
    uint32_t u = __float_as_uint(x);
    u += 0x7FFFu + ((u >> 16) & 1u);
    return (u16)(u >> 16);
}
__device__ __forceinline__ float bf2f(u16 h) {
    return __uint_as_float(((uint32_t)h) << 16);
}
__device__ __forceinline__ float sigm(float x) { return 1.0f / (1.0f + __expf(-x)); }
__device__ __forceinline__ float tanh_fast(float x) {
    float s = __expf(-2.0f * fabsf(x));
    float r = (1.0f - s) / (1.0f + s);
    return copysignf(r, x);
}
__device__ __forceinline__ f32x4 zero4() { f32x4 v = {0.f, 0.f, 0.f, 0.f}; return v; }

__global__ void prep_kernel(const float* __restrict__ Wih0, const float* __restrict__ Whh0,
                            const float* __restrict__ Wih1, const float* __restrict__ Whh1,
                            const float* __restrict__ W1,   const float* __restrict__ W2,
                            const float* __restrict__ W3,   u16* __restrict__ ws,
                            float* __restrict__ out) {
    int tid = blockIdx.x * blockDim.x + threadIdx.x;
    if (tid == 0) out[0] = 0.0f;
    int stride = gridDim.x * blockDim.x;
    for (int i = tid; i < WS_TOTAL; i += stride) {
        int w = i / WAVE_U16, rem = i % WAVE_U16;
        int f = rem >> 9, q = rem & 511, lane = q >> 3, j = q & 7;
        int l16 = lane & 15, kq = lane >> 4, k8 = kq * 8 + j;
        float v = 0.0f;
        if (f < 27) {
            int g = f / 9, kk = f - g * 9;
            int grow = (g * 16 + w) * 16 + l16;
            if (kk < 8) v = Whh0[grow * 256 + kk * 32 + k8];
            else        v = (k8 < YDIM) ? Wih0[grow * YDIM + k8] : 0.0f;
        } else if (f < 75) {
            int ff = f - 27, g = ff >> 4, kk = ff & 15;
            int grow = (g * 16 + w) * 16 + l16;
            if (kk < 8) v = Whh1[grow * 256 + kk * 32 + k8];
            else        v = Wih1[grow * 256 + (kk - 8) * 32 + k8];
        } else if (f < 83) {
            int kt = f - 75, row = w * 16 + l16;
            v = W1[row * 256 + kt * 32 + k8];
        } else if (f < 91) {
            int kt = f - 83, row = w * 16 + l16;
            v = W2[row * 256 + kt * 32 + k8];
        } else {
            int ct = w & 1, kt = w >> 1, r3 = ct * 16 + l16;
            v = (r3 < YDIM) ? W3[r3 * 256 + kt * 32 + k8] : 0.0f;
        }
        ws[i] = f2bf(v);
    }
}

__global__ __launch_bounds__(1024, 1) void rnn_main(
    const float* __restrict__ data,
    const float* __restrict__ bih0g, const float* __restrict__ bhh0g,
    const float* __restrict__ bih1g, const float* __restrict__ bhh1g,
    const float* __restrict__ b1g,  const float* __restrict__ b2g,
    const float* __restrict__ b3g,
    const u16* __restrict__ ws, float* __restrict__ out)
{
    __shared__ u16 sh_h0[16][264];     // recurrent state (stride 264: 2-way = free)
    __shared__ u16 sh_h1[16][264];
    __shared__ u16 sh_d1[16][264];
    __shared__ u16 sh_d2[16][264];
    __shared__ u16 sh_x[16][40];       // x_t, K padded to 32 (cols >=20 stay 0)
    __shared__ u16 lds_w3[16][512];    // W3 frag blocks: block kt*2+ct

    const int tid  = threadIdx.x;
    const int w    = tid >> 6;         // wave 0..15
    const int lane = tid & 63;
    const int l16  = lane & 15;
    const int kq   = lane >> 4;
    const int aoff = kq * 8;
    const int b0   = blockIdx.x * BS;
    const int col  = w * 16 + l16;     // this wave's owned output column

    // ---- load weight fragments into VGPRs (one-time) ----
    const u16* wb = ws + (size_t)w * WAVE_U16;
    bf16x8 fg0[3][9], fg1[3][16], fw1[8], fw2[8];
    #pragma unroll
    for (int g = 0; g < 3; ++g)
        #pragma unroll
        for (int kk = 0; kk < 9; ++kk)
            fg0[g][kk] = *(const bf16x8*)(wb + (g * 9 + kk) * 512 + lane * 8);
    #pragma unroll
    for (int g = 0; g < 3; ++g)
        #pragma unroll
        for (int kk = 0; kk < 16; ++kk)
            fg1[g][kk] = *(const bf16x8*)(wb + (27 + g * 16 + kk) * 512 + lane * 8);
    #pragma unroll
    for (int kt = 0; kt < 8; ++kt) fw1[kt] = *(const bf16x8*)(wb + (75 + kt) * 512 + lane * 8);
    #pragma unroll
    for (int kt = 0; kt < 8; ++kt) fw2[kt] = *(const bf16x8*)(wb + (83 + kt) * 512 + lane * 8);
    {   // W3 frag -> LDS (wave w wrote block index == w; block == kt*2+ct)
        bf16x8 t3 = *(const bf16x8*)(wb + 91 * 512 + lane * 8);
        *(bf16x8*)&lds_w3[w][lane * 8] = t3;
    }

    // ---- init LDS state + stage x(0) ----
    for (int i = tid; i < 16 * 264; i += 1024) { (&sh_h0[0][0])[i] = 0; (&sh_h1[0][0])[i] = 0; }
    for (int i = tid; i < 16 * 40;  i += 1024) (&sh_x[0][0])[i] = 0;
    if (tid < BS * YDIM) sh_x[tid / YDIM][tid % YDIM] = f2bf(data[(size_t)b0 * YDIM + tid]);

    // ---- biases (per-lane, for owned column) ----
    const float bR0 = bih0g[col] + bhh0g[col];
    const float bZ0 = bih0g[col + 256] + bhh0g[col + 256];
    const float bXN0 = bih0g[col + 512], bHN0 = bhh0g[col + 512];
    const float bR1 = bih1g[col] + bhh1g[col];
    const float bZ1 = bih1g[col + 256] + bhh1g[col + 256];
    const float bXN1 = bih1g[col + 512], bHN1 = bhh1g[col + 512];
    const float s1 = b1g[col], s2 = b2g[col];
    const float s3 = (w < 2 && col < YDIM) ? b3g[col] : 0.0f;

    float hr0[4] = {0.f, 0.f, 0.f, 0.f};   // own h-state (bf16-rounded), rows kq*4+q
    float hr1[4] = {0.f, 0.f, 0.f, 0.f};
    float loss = 0.0f;
    __syncthreads();

    #pragma unroll 1
    for (int t = 0; t < T_STEPS - 1; ++t) {
        // ======== Phase A: layer-0 gates ========
        f32x4 aR = zero4(), aZ = zero4(), aXN = zero4(), aHN = zero4();
        #pragma unroll
        for (int kt = 0; kt < 8; ++kt) {
            const bf16x8 A = *(const bf16x8*)&sh_h0[l16][kt * 32 + aoff];
            aR  = MFMA16(A, fg0[0][kt], aR);
            aZ  = MFMA16(A, fg0[1][kt], aZ);
            aHN = MFMA16(A, fg0[2][kt], aHN);
        }
        {
            const bf16x8 Ax = *(const bf16x8*)&sh_x[l16][aoff];
            aR  = MFMA16(Ax, fg0[0][8], aR);
            aZ  = MFMA16(Ax, fg0[1][8], aZ);
            aXN = MFMA16(Ax, fg0[2][8], aXN);
        }
        __syncthreads();                    // B1: all reads of sh_h0 done
        // combine0 (in-register state) -> sh_h0
        #pragma unroll
        for (int q = 0; q < 4; ++q) {
            const float r = sigm(aR[q] + bR0);
            const float z = sigm(aZ[q] + bZ0);
            const float n = tanh_fast(aXN[q] + bXN0 + r * (aHN[q] + bHN0));
            const float hn = (1.0f - z) * n + z * hr0[q];
            const u16 hb = f2bf(hn);
            hr0[q] = bf2f(hb);
            sh_h0[kq * 4 + q][col] = hb;
        }
        __syncthreads();                    // B2: h0(new) ready
        // ======== Phase B: layer-1 gates ========
        aR = zero4(); aZ = zero4(); aXN = zero4(); aHN = zero4();
        #pragma unroll
        for (int kt = 0; kt < 8; ++kt) {
            const bf16x8 A1 = *(const bf16x8*)&sh_h1[l16][kt * 32 + aoff];
            const bf16x8 A0 = *(const bf16x8*)&sh_h0[l16][kt * 32 + aoff];
            aR  = MFMA16(A1, fg1[0][kt], aR);
            aZ  = MFMA16(A1, fg1[1][kt], aZ);
            aHN = MFMA16(A1, fg1[2][kt], aHN);
            aR  = MFMA16(A0, fg1[0][8 + kt], aR);
            aZ  = MFMA16(A0, fg1[1][8 + kt], aZ);
            aXN = MFMA16(A0, fg1[2][8 + kt], aXN);
        }
        __syncthreads();                    // B3: all reads of sh_h1 done
        // combine1 -> sh_h1
        #pragma unroll
        for (int q = 0; q < 4; ++q) {
            const float r = sigm(aR[q] + bR1);
            const float z = sigm(aZ[q] + bZ1);
            const float n = tanh_fast(aXN[q] + bXN1 + r * (aHN[q] + bHN1));
            const float hn = (1.0f - z) * n + z * hr1[q];
            const u16 hb = f2bf(hn);
            hr1[q] = bf2f(hb);
            sh_h1[kq * 4 + q][col] = hb;
        }
        // stage x(t+1) (read next phase A, after B4)
        if (t < T_STEPS - 2 && tid < BS * YDIM)
            sh_x[tid / YDIM][tid % YDIM] =
                f2bf(data[(size_t)(t + 1) * (BATCH * YDIM) + (size_t)b0 * YDIM + tid]);
        __syncthreads();                    // B4: h1(new) + x(t+1) ready
        // prefetch loss targets (hidden under W1/W2 MFMA)
        float tgt0 = 0.f, tgt1 = 0.f, tgt2 = 0.f, tgt3 = 0.f;
        if (w < 2 && col < YDIM) {
            const float* tp = data + (size_t)(t + 1) * (BATCH * YDIM) + (size_t)b0 * YDIM;
            tgt0 = tp[(kq * 4 + 0) * YDIM + col];
            tgt1 = tp[(kq * 4 + 1) * YDIM + col];
            tgt2 = tp[(kq * 4 + 2) * YDIM + col];
            tgt3 = tp[(kq * 4 + 3) * YDIM + col];
        }
        // ======== Phase C: d1 = relu(h1 @ W1^T + b1) ========
        {
            f32x4 d = zero4();
            #pragma unroll
            for (int kt = 0; kt < 8; ++kt) {
                const bf16x8 A = *(const bf16x8*)&sh_h1[l16][kt * 32 + aoff];
                d = MFMA16(A, fw1[kt], d);
            }
            #pragma unroll
            for (int q = 0; q < 4; ++q)
                sh_d1[kq * 4 + q][col] = f2bf(fmaxf(d[q] + s1, 0.0f));
        }
        __syncthreads();                    // B5: d1 ready
        // ======== Phase D: d2 = relu(d1 @ W2^T + b2) ========
        {
            f32x4 d = zero4();
            #pragma unroll
            for (int kt = 0; kt < 8; ++kt) {
                const bf16x8 A = *(const bf16x8*)&sh_d1[l16][kt * 32 + aoff];
                d = MFMA16(A, fw2[kt], d);
            }
            #pragma unroll
            for (int q = 0; q < 4; ++q)
                sh_d2[kq * 4 + q][col] = f2bf(fmaxf(d[q] + s2, 0.0f));
        }
        __syncthreads();                    // B6: d2 ready
        // ======== Phase E: d3 + loss (waves 0,1; overlaps next step's phase A) ========
        if (w < 2) {
            f32x4 lacc = zero4();
            #pragma unroll
            for (int kt = 0; kt < 8; ++kt) {
                const bf16x8 A = *(const bf16x8*)&sh_d2[l16][kt * 32 + aoff];
                const bf16x8 B = *(const bf16x8*)&lds_w3[kt * 2 + w][lane * 8];
                lacc = MFMA16(A, B, lacc);
            }
            if (col < YDIM) {
                const float e0 = lacc[0] + s3 - tgt0;
                const float e1 = lacc[1] + s3 - tgt1;
                const float e2 = lacc[2] + s3 - tgt2;
                const float e3 = lacc[3] + s3 - tgt3;
                loss += e0 * e0 + e1 * e1 + e2 * e2 + e3 * e3;
            }
        }
        // no barrier: phase A(t+1) only reads sh_h0/h1/x; first write is after B1(t+1)
    }

    #pragma unroll
    for (int s = 32; s > 0; s >>= 1) loss += __shfl_down(loss, s, 64);
    if (lane == 0 && w < 2) atomicAdd(out, loss);
}

extern "C" void kernel_launch(void* const* d_in, const int* in_sizes, int n_in,
                              void* d_out, int out_size, void* d_ws, size_t ws_size,
                              hipStream_t stream) {
    const float* data = (const float*)d_in[0];
    const float* Wih0 = (const float*)d_in[1];
    const float* Whh0 = (const float*)d_in[2];
    const float* bih0 = (const float*)d_in[3];
    const float* bhh0 = (const float*)d_in[4];
    const float* Wih1 = (const float*)d_in[5];
    const float* Whh1 = (const float*)d_in[6];
    const float* bih1 = (const float*)d_in[7];
    const float* bhh1 = (const float*)d_in[8];
    const float* W1   = (const float*)d_in[9];
    const float* b1   = (const float*)d_in[10];
    const float* W2   = (const float*)d_in[11];
    const float* b2   = (const float*)d_in[12];
    const float* W3   = (const float*)d_in[13];
    const float* b3   = (const float*)d_in[14];
    u16*   ws  = (u16*)d_ws;
    float* out = (float*)d_out;

    hipLaunchKernelGGL(prep_kernel, dim3(512), dim3(256), 0, stream,
                       Wih0, Whh0, Wih1, Whh1, W1, W2, W3, ws, out);
    hipLaunchKernelGGL(rnn_main, dim3(NWG), dim3(1024), 0, stream,
                       data, bih0, bhh0, bih1, bhh1, b1, b2, b3, ws, out);
}